// Round 1
// baseline (921.408 us; speedup 1.0000x reference)
//
#include <hip/hip_runtime.h>
#include <math.h>

// Problem constants
#define B  16384
#define K  1024
#define D  512
#define TAU_INV 10.0f
#define EPS 1e-12f

// d_out layout (floats): [0, B*D) pt ; [B*D, B*D+K*D) p ; then sim_loss, div_loss
#define OUT_PT   0
#define OUT_P    (B*D)
#define OUT_SIM  (B*D + K*D)
#define OUT_DIV  (B*D + K*D + 1)

// ws layout (floats): [0]=sum e*sim, [1]=||colsum||^2, [2]=diag sum,
// [16, 16+B) inv_norm_x, simbuf at float offset 32768 (B*K floats)
#define WS_DOT   0
#define WS_SSQ   1
#define WS_DIAG  2
#define WS_INVN  16
#define WS_SIM   32768

__device__ __forceinline__ float wave_reduce_sum(float v) {
    #pragma unroll
    for (int off = 32; off >= 1; off >>= 1) v += __shfl_down(v, off);
    return v;
}
__device__ __forceinline__ float wave_reduce_max(float v) {
    #pragma unroll
    for (int off = 32; off >= 1; off >>= 1) v = fmaxf(v, __shfl_down(v, off));
    return v;
}

__global__ void zero_scalars(float* ws) {
    if (threadIdx.x < 3) ws[threadIdx.x] = 0.0f;
}

// Normalize prototypes: one wave per row. Writes p to d_out, accumulates diag sum.
__global__ __launch_bounds__(256) void norm_p_kernel(const float* __restrict__ proto,
                                                     float* __restrict__ out,
                                                     float* __restrict__ ws) {
    int wid = threadIdx.x >> 6, lane = threadIdx.x & 63;
    int row = blockIdx.x * 4 + wid;
    const float4* pr = (const float4*)(proto + (size_t)row * D);
    float4 a = pr[lane * 2], b = pr[lane * 2 + 1];
    float ss = a.x*a.x + a.y*a.y + a.z*a.z + a.w*a.w
             + b.x*b.x + b.y*b.y + b.z*b.z + b.w*b.w;
    ss = wave_reduce_sum(ss);
    ss = __shfl(ss, 0);
    float inv = 1.0f / fmaxf(sqrtf(ss), EPS);
    float4* po = (float4*)(out + OUT_P + (size_t)row * D);
    float4 na = make_float4(a.x*inv, a.y*inv, a.z*inv, a.w*inv);
    float4 nb = make_float4(b.x*inv, b.y*inv, b.z*inv, b.w*inv);
    po[lane * 2] = na;
    po[lane * 2 + 1] = nb;
    if (lane == 0) atomicAdd(ws + WS_DIAG, ss * inv * inv);
}

// Column sums of normalized p -> ||s||^2 accumulated into ws[WS_SSQ]
__global__ __launch_bounds__(256) void col_reduce_kernel(const float* __restrict__ out,
                                                         float* __restrict__ ws) {
    int d = blockIdx.x * 256 + threadIdx.x;
    const float* p = out + OUT_P;
    float s = 0.0f;
    #pragma unroll 8
    for (int k = 0; k < K; ++k) s += p[(size_t)k * D + d];
    float v = s * s;
    // block reduce
    __shared__ float red[4];
    float w = wave_reduce_sum(v);
    int wid = threadIdx.x >> 6, lane = threadIdx.x & 63;
    if (lane == 0) red[wid] = w;
    __syncthreads();
    if (threadIdx.x == 0) {
        atomicAdd(ws + WS_SSQ, red[0] + red[1] + red[2] + red[3]);
    }
}

// inv row norms of input: one wave per row
__global__ __launch_bounds__(256) void row_norms_x(const float* __restrict__ x,
                                                   float* __restrict__ ws) {
    int wid = threadIdx.x >> 6, lane = threadIdx.x & 63;
    int row = blockIdx.x * 4 + wid;
    const float4* xr = (const float4*)(x + (size_t)row * D);
    float4 a = xr[lane * 2], b = xr[lane * 2 + 1];
    float ss = a.x*a.x + a.y*a.y + a.z*a.z + a.w*a.w
             + b.x*b.x + b.y*b.y + b.z*b.z + b.w*b.w;
    ss = wave_reduce_sum(ss);
    if (lane == 0) ws[WS_INVN + row] = 1.0f / fmaxf(sqrtf(ss), EPS);
}

// GEMM1: sim[B][K] = xhat @ phat^T. Block tile 128(b) x 128(k), 8x8 microtile,
// reduction over D in chunks of 32 staged in LDS.
__global__ __launch_bounds__(256) void gemm1_sim(const float* __restrict__ x,
                                                 const float* __restrict__ out, // p at OUT_P
                                                 float* __restrict__ ws) {
    __shared__ float Xs[128][33];
    __shared__ float Ps[128][33];
    const float* p = out + OUT_P;
    float* sim = ws + WS_SIM;
    const float* invn = ws + WS_INVN;

    int tid = threadIdx.x;
    int tx = tid & 15, ty = tid >> 4;
    int k0 = blockIdx.x * 128;
    int b0 = blockIdx.y * 128;

    float acc[8][8];
    #pragma unroll
    for (int i = 0; i < 8; ++i)
        #pragma unroll
        for (int j = 0; j < 8; ++j) acc[i][j] = 0.0f;

    for (int dc = 0; dc < D; dc += 32) {
        #pragma unroll
        for (int q = 0; q < 4; ++q) {
            int lin = tid + 256 * q;          // 0..1023
            int row = lin >> 3;               // 0..127
            int c4 = (lin & 7) * 4;           // 0..28
            float4 xv = *(const float4*)(x + (size_t)(b0 + row) * D + dc + c4);
            float sc = invn[b0 + row];
            Xs[row][c4 + 0] = xv.x * sc;
            Xs[row][c4 + 1] = xv.y * sc;
            Xs[row][c4 + 2] = xv.z * sc;
            Xs[row][c4 + 3] = xv.w * sc;
            float4 pv = *(const float4*)(p + (size_t)(k0 + row) * D + dc + c4);
            Ps[row][c4 + 0] = pv.x;
            Ps[row][c4 + 1] = pv.y;
            Ps[row][c4 + 2] = pv.z;
            Ps[row][c4 + 3] = pv.w;
        }
        __syncthreads();
        #pragma unroll 2
        for (int d = 0; d < 32; ++d) {
            float xv[8], pv[8];
            #pragma unroll
            for (int i = 0; i < 8; ++i) xv[i] = Xs[ty + 16 * i][d];
            #pragma unroll
            for (int j = 0; j < 8; ++j) pv[j] = Ps[tx + 16 * j][d];
            #pragma unroll
            for (int i = 0; i < 8; ++i)
                #pragma unroll
                for (int j = 0; j < 8; ++j)
                    acc[i][j] = fmaf(xv[i], pv[j], acc[i][j]);
        }
        __syncthreads();
    }
    #pragma unroll
    for (int i = 0; i < 8; ++i) {
        size_t rbase = (size_t)(b0 + ty + 16 * i) * K + k0;
        #pragma unroll
        for (int j = 0; j < 8; ++j)
            sim[rbase + tx + 16 * j] = acc[i][j];
    }
}

// Row softmax with gumbel; writes e in-place over sim; accumulates sum(e*sim).
__global__ __launch_bounds__(256) void softmax_rows(const float* __restrict__ u,
                                                    float* __restrict__ ws) {
    float* simbuf = ws + WS_SIM;
    int row = blockIdx.x;
    int tid = threadIdx.x;
    float4* srow = (float4*)(simbuf + (size_t)row * K);
    const float4* urow = (const float4*)(u + (size_t)row * K);
    float4 s = srow[tid];
    float4 uu = urow[tid];
    float4 z;
    z.x = (s.x - logf(-logf(uu.x))) * TAU_INV;
    z.y = (s.y - logf(-logf(uu.y))) * TAU_INV;
    z.z = (s.z - logf(-logf(uu.z))) * TAU_INV;
    z.w = (s.w - logf(-logf(uu.w))) * TAU_INV;

    __shared__ float red[4];
    int wid = tid >> 6, lane = tid & 63;

    float m = fmaxf(fmaxf(z.x, z.y), fmaxf(z.z, z.w));
    m = wave_reduce_max(m);
    if (lane == 0) red[wid] = m;
    __syncthreads();
    float M = fmaxf(fmaxf(red[0], red[1]), fmaxf(red[2], red[3]));
    __syncthreads();

    float4 e;
    e.x = expf(z.x - M);
    e.y = expf(z.y - M);
    e.z = expf(z.z - M);
    e.w = expf(z.w - M);
    float l = e.x + e.y + e.z + e.w;
    l = wave_reduce_sum(l);
    if (lane == 0) red[wid] = l;
    __syncthreads();
    float L = red[0] + red[1] + red[2] + red[3];
    float inv = 1.0f / L;
    e.x *= inv; e.y *= inv; e.z *= inv; e.w *= inv;
    srow[tid] = e;

    float dot = e.x * s.x + e.y * s.y + e.z * s.z + e.w * s.w;
    dot = wave_reduce_sum(dot);
    __syncthreads();
    if (lane == 0) red[wid] = dot;
    __syncthreads();
    if (tid == 0) atomicAdd(ws + WS_DOT, red[0] + red[1] + red[2] + red[3]);
}

// GEMM2: pt[B][D] = e @ p. Block tile 128(b) x 128(d), 8x8 microtile,
// reduction over K in chunks of 32.
__global__ __launch_bounds__(256) void gemm2_pt(float* __restrict__ out,
                                                const float* __restrict__ ws) {
    __shared__ float Es[128][33];
    __shared__ float Ps2[32][129];
    const float* e = ws + WS_SIM;
    const float* p = out + OUT_P;
    float* pt = out + OUT_PT;

    int tid = threadIdx.x;
    int tx = tid & 15, ty = tid >> 4;
    int d0 = blockIdx.x * 128;
    int b0 = blockIdx.y * 128;

    float acc[8][8];
    #pragma unroll
    for (int i = 0; i < 8; ++i)
        #pragma unroll
        for (int j = 0; j < 8; ++j) acc[i][j] = 0.0f;

    for (int kc = 0; kc < K; kc += 32) {
        #pragma unroll
        for (int q = 0; q < 4; ++q) {
            int lin = tid + 256 * q;          // 0..1023
            int row = lin >> 3;               // 0..127 (b)
            int c4 = (lin & 7) * 4;           // 0..28 (k)
            float4 ev = *(const float4*)(e + (size_t)(b0 + row) * K + kc + c4);
            Es[row][c4 + 0] = ev.x;
            Es[row][c4 + 1] = ev.y;
            Es[row][c4 + 2] = ev.z;
            Es[row][c4 + 3] = ev.w;
            int prow = lin >> 5;              // 0..31 (k)
            int pc4 = (lin & 31) * 4;         // 0..124 (d)
            float4 pv = *(const float4*)(p + (size_t)(kc + prow) * D + d0 + pc4);
            Ps2[prow][pc4 + 0] = pv.x;
            Ps2[prow][pc4 + 1] = pv.y;
            Ps2[prow][pc4 + 2] = pv.z;
            Ps2[prow][pc4 + 3] = pv.w;
        }
        __syncthreads();
        #pragma unroll 2
        for (int kk = 0; kk < 32; ++kk) {
            float ev[8], pv[8];
            #pragma unroll
            for (int i = 0; i < 8; ++i) ev[i] = Es[ty + 16 * i][kk];
            #pragma unroll
            for (int j = 0; j < 8; ++j) pv[j] = Ps2[kk][tx + 16 * j];
            #pragma unroll
            for (int i = 0; i < 8; ++i)
                #pragma unroll
                for (int j = 0; j < 8; ++j)
                    acc[i][j] = fmaf(ev[i], pv[j], acc[i][j]);
        }
        __syncthreads();
    }
    #pragma unroll
    for (int i = 0; i < 8; ++i) {
        size_t rbase = (size_t)(b0 + ty + 16 * i) * D + d0;
        #pragma unroll
        for (int j = 0; j < 8; ++j)
            pt[rbase + tx + 16 * j] = acc[i][j];
    }
}

__global__ void finalize_kernel(float* __restrict__ out, const float* __restrict__ ws) {
    if (threadIdx.x == 0) {
        out[OUT_SIM] = 1.0f - ws[WS_DOT] * (1.0f / (float)B);
        out[OUT_DIV] = ws[WS_SSQ] - ws[WS_DIAG];
    }
}

extern "C" void kernel_launch(void* const* d_in, const int* in_sizes, int n_in,
                              void* d_out, int out_size, void* d_ws, size_t ws_size,
                              hipStream_t stream) {
    const float* input = (const float*)d_in[0];
    const float* proto = (const float*)d_in[1];
    const float* gumbel = (const float*)d_in[2];
    float* out = (float*)d_out;
    float* ws = (float*)d_ws;

    zero_scalars<<<1, 64, 0, stream>>>(ws);
    norm_p_kernel<<<K / 4, 256, 0, stream>>>(proto, out, ws);
    col_reduce_kernel<<<D / 256, 256, 0, stream>>>(out, ws);
    row_norms_x<<<B / 4, 256, 0, stream>>>(input, ws);
    {
        dim3 grid(K / 128, B / 128);
        gemm1_sim<<<grid, 256, 0, stream>>>(input, out, ws);
    }
    softmax_rows<<<B, 256, 0, stream>>>(gumbel, ws);
    {
        dim3 grid(D / 128, B / 128);
        gemm2_pt<<<grid, 256, 0, stream>>>(out, ws);
    }
    finalize_kernel<<<1, 64, 0, stream>>>(out, ws);
}

// Round 2
// 573.662 us; speedup vs baseline: 1.6062x; 1.6062x over previous
//
#include <hip/hip_runtime.h>
#include <hip/hip_bf16.h>
#include <math.h>

// Problem constants
#define B  16384
#define K  1024
#define D  512
#define TAU_INV 10.0f
#define EPS 1e-12f

typedef unsigned short ushort_t;

// d_out layout (floats): [0, B*D) pt ; [B*D, B*D+K*D) p ; then sim_loss, div_loss
#define OUT_PT   0
#define OUT_P    (B*D)
#define OUT_SIM  (B*D + K*D)
#define OUT_DIV  (B*D + K*D + 1)

// ws layout (floats):
//  [0..16)    scalars: 0=sum e*sim, 1=||colsum||^2, 2=diag sum
//  [32768, 32768+B*K) sim fp32; after softmax the SAME bytes hold Esplit bf16
//             (row: 1024 hi | 1024 lo; 4KB/row either way)
//  then Psplit  [1024][1024] ushort (row k: hi(512)|lo(512))   = 2 MB
//  then PTsplit [512][2048] ushort (row d: hi(k=0..1023)|lo)   = 2 MB
#define WS_DOT   0
#define WS_SSQ   1
#define WS_DIAG  2
#define WS_SIM   32768
#define WS_PS    (WS_SIM + B*K)            // float offset; cast to ushort*
#define WS_PTS   (WS_PS + (K*K)/2)         // K*K ushorts = K*K/2 floats

// Xsplit bf16 [16384][1024] (hi|lo) lives in d_out's pt region (same 33.55 MB),
// consumed by gemm1 before gemm2 overwrites pt.

typedef __bf16 bf16x8 __attribute__((ext_vector_type(8)));
typedef float f32x4 __attribute__((ext_vector_type(4)));

__device__ __forceinline__ float wave_reduce_sum(float v) {
    #pragma unroll
    for (int off = 32; off >= 1; off >>= 1) v += __shfl_down(v, off);
    return v;
}
__device__ __forceinline__ float wave_reduce_max(float v) {
    #pragma unroll
    for (int off = 32; off >= 1; off >>= 1) v = fmaxf(v, __shfl_down(v, off));
    return v;
}

__device__ __forceinline__ ushort_t f2bf(float f) {
    __hip_bfloat16 h = __float2bfloat16(f);
    return *reinterpret_cast<ushort_t*>(&h);
}
__device__ __forceinline__ float bf2f(ushort_t u) {
    __hip_bfloat16 h;
    *reinterpret_cast<ushort_t*>(&h) = u;
    return __bfloat162float(h);
}

__device__ __forceinline__ void async16(const void* g, void* l) {
    __builtin_amdgcn_global_load_lds(
        (const __attribute__((address_space(1))) unsigned int*)g,
        (__attribute__((address_space(3))) unsigned int*)l, 16, 0, 0);
}

__global__ void zero_scalars(float* ws) {
    if (threadIdx.x < 3) ws[threadIdx.x] = 0.0f;
}

// Normalize prototypes: one wave per row. Writes phat (fp32) to d_out, accumulates diag sum.
__global__ __launch_bounds__(256) void norm_p_kernel(const float* __restrict__ proto,
                                                     float* __restrict__ out,
                                                     float* __restrict__ ws) {
    int wid = threadIdx.x >> 6, lane = threadIdx.x & 63;
    int row = blockIdx.x * 4 + wid;
    const float4* pr = (const float4*)(proto + (size_t)row * D);
    float4 a = pr[lane * 2], b = pr[lane * 2 + 1];
    float ss = a.x*a.x + a.y*a.y + a.z*a.z + a.w*a.w
             + b.x*b.x + b.y*b.y + b.z*b.z + b.w*b.w;
    ss = wave_reduce_sum(ss);
    ss = __shfl(ss, 0);
    float inv = 1.0f / fmaxf(sqrtf(ss), EPS);
    float4* po = (float4*)(out + OUT_P + (size_t)row * D);
    po[lane * 2]     = make_float4(a.x*inv, a.y*inv, a.z*inv, a.w*inv);
    po[lane * 2 + 1] = make_float4(b.x*inv, b.y*inv, b.z*inv, b.w*inv);
    if (lane == 0) atomicAdd(ws + WS_DIAG, ss * inv * inv);
}

// Psplit [1024][1024]: row k = [hi(phat[k][0..512)) | lo(...)]
__global__ __launch_bounds__(256) void psplit_kernel(const float* __restrict__ out,
                                                     ushort_t* __restrict__ Ps) {
    int k = blockIdx.x, tid = threadIdx.x;
    const float2* pr = (const float2*)(out + OUT_P + (size_t)k * D);
    float2 v = pr[tid];
    ushort_t h0 = f2bf(v.x), h1 = f2bf(v.y);
    ushort_t l0 = f2bf(v.x - bf2f(h0)), l1 = f2bf(v.y - bf2f(h1));
    *(ushort2*)(Ps + (size_t)k * 1024 + 2 * tid)       = make_ushort2(h0, h1);
    *(ushort2*)(Ps + (size_t)k * 1024 + 512 + 2 * tid) = make_ushort2(l0, l1);
}

// PTsplit [512][2048]: row d = [hi(phat[0..1024)[d]) | lo(...)] (transpose of phat)
__global__ __launch_bounds__(256) void ptsplit_kernel(const float* __restrict__ out,
                                                      ushort_t* __restrict__ PT) {
    __shared__ float tile[64][65];
    int k0 = blockIdx.x * 64, d0 = blockIdx.y * 64;
    int tid = threadIdx.x;
    const float* phat = out + OUT_P;
    #pragma unroll
    for (int i = tid; i < 64 * 64; i += 256) {
        int kk = i >> 6, dd = i & 63;
        tile[dd][kk] = phat[(size_t)(k0 + kk) * D + d0 + dd];
    }
    __syncthreads();
    #pragma unroll
    for (int i = tid; i < 64 * 64; i += 256) {
        int dd = i >> 6, kk = i & 63;
        float f = tile[dd][kk];
        ushort_t hi = f2bf(f);
        ushort_t lo = f2bf(f - bf2f(hi));
        PT[(size_t)(d0 + dd) * 2048 + k0 + kk]        = hi;
        PT[(size_t)(d0 + dd) * 2048 + 1024 + k0 + kk] = lo;
    }
}

// Column sums of phat -> ||s||^2 accumulated into ws[WS_SSQ]
__global__ __launch_bounds__(256) void col_reduce_kernel(const float* __restrict__ out,
                                                         float* __restrict__ ws) {
    int d = blockIdx.x * 256 + threadIdx.x;
    const float* p = out + OUT_P;
    float s = 0.0f;
    #pragma unroll 8
    for (int k = 0; k < K; ++k) s += p[(size_t)k * D + d];
    float v = s * s;
    __shared__ float red[4];
    float w = wave_reduce_sum(v);
    int wid = threadIdx.x >> 6, lane = threadIdx.x & 63;
    if (lane == 0) red[wid] = w;
    __syncthreads();
    if (threadIdx.x == 0) atomicAdd(ws + WS_SSQ, red[0] + red[1] + red[2] + red[3]);
}

// Fused x row-norm + split: Xsplit [16384][1024] ushort (hi(512)|lo(512)) in out's pt region
__global__ __launch_bounds__(256) void xsplit_kernel(const float* __restrict__ x,
                                                     ushort_t* __restrict__ Xs) {
    int row = blockIdx.x, tid = threadIdx.x;
    const float2* xr = (const float2*)(x + (size_t)row * D);
    float2 v = xr[tid];
    float ss = v.x * v.x + v.y * v.y;
    __shared__ float red[4];
    float w = wave_reduce_sum(ss);
    int wid = tid >> 6, lane = tid & 63;
    if (lane == 0) red[wid] = w;
    __syncthreads();
    float tot = red[0] + red[1] + red[2] + red[3];
    float inv = 1.0f / fmaxf(sqrtf(tot), EPS);
    float a = v.x * inv, b = v.y * inv;
    ushort_t h0 = f2bf(a), h1 = f2bf(b);
    ushort_t l0 = f2bf(a - bf2f(h0)), l1 = f2bf(b - bf2f(h1));
    *(ushort2*)(Xs + (size_t)row * 1024 + 2 * tid)       = make_ushort2(h0, h1);
    *(ushort2*)(Xs + (size_t)row * 1024 + 512 + 2 * tid) = make_ushort2(l0, l1);
}

// Split-bf16 bt-GEMM (m97 recipe): C[m][n] = sum over 3 segments of A(seg)·B(seg)^T.
// 128x128 block tile, 4 waves, 4x4 16x16x32-MFMA tiles per wave, BK=32,
// global_load_lds width-16 staging, single LDS buffer (2-barrier K-loop).
template<int LDA, int LDB, int LDC, int SEGK>
__global__ __launch_bounds__(256) void gemm_bt(const ushort_t* __restrict__ A,
                                               const ushort_t* __restrict__ Bm,
                                               float* __restrict__ C,
                                               int a0, int a1, int a2,
                                               int b0, int b1, int b2) {
    __shared__ __align__(16) ushort_t As[128 * 32];
    __shared__ __align__(16) ushort_t Bs[128 * 32];
    int tid = threadIdx.x;
    int wid = tid >> 6, lane = tid & 63;
    int quad = lane >> 4, l16 = lane & 15;
    int wm = (wid & 1) * 64, wn = (wid >> 1) * 64;
    int bn0 = blockIdx.x * 128, bm0 = blockIdx.y * 128;
    int ldrow = lane >> 2;           // 0..15
    int lcol  = (lane & 3) * 8;      // element offset within 32-col tile row

    f32x4 acc[4][4] = {};

    // wave-uniform LDS staging bases (1024 B per wave-issue)
    ushort_t* AsW0 = As + (wid * 16) * 32;
    ushort_t* AsW1 = As + (64 + wid * 16) * 32;
    ushort_t* BsW0 = Bs + (wid * 16) * 32;
    ushort_t* BsW1 = Bs + (64 + wid * 16) * 32;

    int aoff[3] = {a0, a1, a2};
    int boff[3] = {b0, b1, b2};

    for (int s = 0; s < 3; ++s) {
        const ushort_t* Ab = A + aoff[s] + (size_t)(bm0 + wid * 16 + ldrow) * LDA + lcol;
        const ushort_t* Bb = Bm + boff[s] + (size_t)(bn0 + wid * 16 + ldrow) * LDB + lcol;
        for (int kc = 0; kc < SEGK; kc += 32) {
            async16(Ab + kc, AsW0);
            async16(Ab + kc + (size_t)64 * LDA, AsW1);
            async16(Bb + kc, BsW0);
            async16(Bb + kc + (size_t)64 * LDB, BsW1);
            __syncthreads();
            bf16x8 af[4], bg[4];
            #pragma unroll
            for (int i = 0; i < 4; ++i)
                af[i] = *(const bf16x8*)(As + (wm + 16 * i + l16) * 32 + quad * 8);
            #pragma unroll
            for (int j = 0; j < 4; ++j)
                bg[j] = *(const bf16x8*)(Bs + (wn + 16 * j + l16) * 32 + quad * 8);
            #pragma unroll
            for (int i = 0; i < 4; ++i)
                #pragma unroll
                for (int j = 0; j < 4; ++j)
                    acc[i][j] = __builtin_amdgcn_mfma_f32_16x16x32_bf16(af[i], bg[j], acc[i][j], 0, 0, 0);
            __syncthreads();
        }
    }
    #pragma unroll
    for (int i = 0; i < 4; ++i) {
        #pragma unroll
        for (int j = 0; j < 4; ++j) {
            #pragma unroll
            for (int r = 0; r < 4; ++r) {
                int row = bm0 + wm + 16 * i + quad * 4 + r;
                int col = bn0 + wn + 16 * j + l16;
                C[(size_t)row * LDC + col] = acc[i][j][r];
            }
        }
    }
}

// Row softmax with gumbel; reads sim fp32, writes Esplit bf16 (hi|lo) IN-PLACE
// over the same row bytes; accumulates sum(e*sim).
__global__ __launch_bounds__(256) void softmax_rows(const float* __restrict__ u,
                                                    float* __restrict__ ws) {
    float* simbuf = ws + WS_SIM;
    int row = blockIdx.x, tid = threadIdx.x;
    float4* srow = (float4*)(simbuf + (size_t)row * K);
    const float4* urow = (const float4*)(u + (size_t)row * K);
    float4 s = srow[tid];
    float4 uu = urow[tid];
    float4 z;
    z.x = (s.x - logf(-logf(uu.x))) * TAU_INV;
    z.y = (s.y - logf(-logf(uu.y))) * TAU_INV;
    z.z = (s.z - logf(-logf(uu.z))) * TAU_INV;
    z.w = (s.w - logf(-logf(uu.w))) * TAU_INV;

    __shared__ float red[4];
    int wid = tid >> 6, lane = tid & 63;

    float m = fmaxf(fmaxf(z.x, z.y), fmaxf(z.z, z.w));
    m = wave_reduce_max(m);
    if (lane == 0) red[wid] = m;
    __syncthreads();
    float M = fmaxf(fmaxf(red[0], red[1]), fmaxf(red[2], red[3]));
    __syncthreads();

    float4 e;
    e.x = expf(z.x - M);
    e.y = expf(z.y - M);
    e.z = expf(z.z - M);
    e.w = expf(z.w - M);
    float l = e.x + e.y + e.z + e.w;
    l = wave_reduce_sum(l);
    if (lane == 0) red[wid] = l;
    __syncthreads();
    float L = red[0] + red[1] + red[2] + red[3];
    float inv = 1.0f / L;
    e.x *= inv; e.y *= inv; e.z *= inv; e.w *= inv;

    float dot = e.x * s.x + e.y * s.y + e.z * s.z + e.w * s.w;

    // in-place split write (all reads of srow completed before first barrier)
    ushort_t* erow = (ushort_t*)(simbuf + (size_t)row * K);
    ushort_t h0 = f2bf(e.x), h1 = f2bf(e.y), h2 = f2bf(e.z), h3 = f2bf(e.w);
    ushort4 hi4 = make_ushort4(h0, h1, h2, h3);
    ushort4 lo4 = make_ushort4(f2bf(e.x - bf2f(h0)), f2bf(e.y - bf2f(h1)),
                               f2bf(e.z - bf2f(h2)), f2bf(e.w - bf2f(h3)));
    *(ushort4*)(erow + 4 * tid)        = hi4;
    *(ushort4*)(erow + 1024 + 4 * tid) = lo4;

    dot = wave_reduce_sum(dot);
    __syncthreads();
    if (lane == 0) red[wid] = dot;
    __syncthreads();
    if (tid == 0) atomicAdd(ws + WS_DOT, red[0] + red[1] + red[2] + red[3]);
}

__global__ void finalize_kernel(float* __restrict__ out, const float* __restrict__ ws) {
    if (threadIdx.x == 0) {
        out[OUT_SIM] = 1.0f - ws[WS_DOT] * (1.0f / (float)B);
        out[OUT_DIV] = ws[WS_SSQ] - ws[WS_DIAG];
    }
}

extern "C" void kernel_launch(void* const* d_in, const int* in_sizes, int n_in,
                              void* d_out, int out_size, void* d_ws, size_t ws_size,
                              hipStream_t stream) {
    const float* input  = (const float*)d_in[0];
    const float* proto  = (const float*)d_in[1];
    const float* gumbel = (const float*)d_in[2];
    float* out = (float*)d_out;
    float* ws  = (float*)d_ws;

    ushort_t* Xs  = (ushort_t*)(out + OUT_PT);     // Xsplit scratch in pt region
    ushort_t* Ps  = (ushort_t*)(ws + WS_PS);
    ushort_t* PTs = (ushort_t*)(ws + WS_PTS);
    ushort_t* Es  = (ushort_t*)(ws + WS_SIM);      // Esplit aliases sim rows
    float* sim = ws + WS_SIM;

    zero_scalars<<<1, 64, 0, stream>>>(ws);
    norm_p_kernel<<<K / 4, 256, 0, stream>>>(proto, out, ws);
    psplit_kernel<<<K, 256, 0, stream>>>(out, Ps);
    {
        dim3 grid(K / 64, D / 64);
        ptsplit_kernel<<<grid, 256, 0, stream>>>(out, PTs);
    }
    col_reduce_kernel<<<D / 256, 256, 0, stream>>>(out, ws);
    xsplit_kernel<<<B, 256, 0, stream>>>(input, Xs);
    {
        // sim = Xhi·Phi^T + Xhi·Plo^T + Xlo·Phi^T
        dim3 grid(K / 128, B / 128);
        gemm_bt<1024, 1024, K, 512><<<grid, 256, 0, stream>>>(
            Xs, Ps, sim, 0, 0, 512, 0, 512, 0);
    }
    softmax_rows<<<B, 256, 0, stream>>>(gumbel, ws);
    {
        // pt = Ehi·PThi^T + Elo·PThi^T + Ehi·PTlo^T
        dim3 grid(D / 128, B / 128);
        gemm_bt<2048, 2048, D, 1024><<<grid, 256, 0, stream>>>(
            Es, PTs, out + OUT_PT, 0, 1024, 0, 0, 0, 1024);
    }
    finalize_kernel<<<1, 64, 0, stream>>>(out, ws);
}

// Round 3
// 395.864 us; speedup vs baseline: 2.3276x; 1.4491x over previous
//
#include <hip/hip_runtime.h>
#include <hip/hip_bf16.h>
#include <math.h>

// Problem constants
#define B  16384
#define K  1024
#define D  512
#define TAU_INV 10.0f
#define EPS 1e-12f

typedef unsigned short ushort_t;

// d_out layout (floats): [0, B*D) pt ; [B*D, B*D+K*D) p ; then sim_loss, div_loss
#define OUT_PT   0
#define OUT_P    (B*D)
#define OUT_SIM  (B*D + K*D)
#define OUT_DIV  (B*D + K*D + 1)

// ws layout (floats):
//  [0..16)      scalars: 1=||colsum||^2, 2=diag sum
//  [1024,2048)  softmax per-block dot partials (1024 floats)
//  [32768, 32768+B*K) sim fp32; after softmax SAME bytes hold Esplit bf16
//               (row: 1024 hi | 1024 lo; 4KB/row either way)
//  then Psplit  [1024][1024] ushort (row k: hi(512)|lo(512))   = 2 MB
//  then PTsplit [512][2048] ushort (row d: hi(k)|lo(k))        = 2 MB
#define WS_SSQ   1
#define WS_DIAG  2
#define WS_RED   1024
#define WS_SIM   32768
#define WS_PS    (WS_SIM + B*K)
#define WS_PTS   (WS_PS + (K*K)/2)

typedef __bf16 bf16x8 __attribute__((ext_vector_type(8)));
typedef float f32x4 __attribute__((ext_vector_type(4)));

__device__ __forceinline__ float wave_reduce_sum(float v) {
    #pragma unroll
    for (int off = 32; off >= 1; off >>= 1) v += __shfl_down(v, off);
    return v;
}
__device__ __forceinline__ float wave_reduce_max(float v) {
    #pragma unroll
    for (int off = 32; off >= 1; off >>= 1) v = fmaxf(v, __shfl_down(v, off));
    return v;
}

__device__ __forceinline__ ushort_t f2bf(float f) {
    __hip_bfloat16 h = __float2bfloat16(f);
    return *reinterpret_cast<ushort_t*>(&h);
}
__device__ __forceinline__ float bf2f(ushort_t u) {
    __hip_bfloat16 h;
    *reinterpret_cast<ushort_t*>(&h) = u;
    return __bfloat162float(h);
}

__device__ __forceinline__ void async16(const void* g, void* l) {
    __builtin_amdgcn_global_load_lds(
        (const __attribute__((address_space(1))) unsigned int*)g,
        (__attribute__((address_space(3))) unsigned int*)l, 16, 0, 0);
}

__global__ void zero_scalars(float* ws) {
    if (threadIdx.x < 3) ws[threadIdx.x] = 0.0f;
}

// Normalize prototypes: one wave per row. Writes phat (fp32) to d_out.
// One atomic per BLOCK (LDS-combined) for the diag sum.
__global__ __launch_bounds__(256) void norm_p_kernel(const float* __restrict__ proto,
                                                     float* __restrict__ out,
                                                     float* __restrict__ ws) {
    int wid = threadIdx.x >> 6, lane = threadIdx.x & 63;
    int row = blockIdx.x * 4 + wid;
    const float4* pr = (const float4*)(proto + (size_t)row * D);
    float4 a = pr[lane * 2], b = pr[lane * 2 + 1];
    float ss = a.x*a.x + a.y*a.y + a.z*a.z + a.w*a.w
             + b.x*b.x + b.y*b.y + b.z*b.z + b.w*b.w;
    ss = wave_reduce_sum(ss);
    ss = __shfl(ss, 0);
    float inv = 1.0f / fmaxf(sqrtf(ss), EPS);
    float4* po = (float4*)(out + OUT_P + (size_t)row * D);
    po[lane * 2]     = make_float4(a.x*inv, a.y*inv, a.z*inv, a.w*inv);
    po[lane * 2 + 1] = make_float4(b.x*inv, b.y*inv, b.z*inv, b.w*inv);
    __shared__ float red[4];
    if (lane == 0) red[wid] = ss * inv * inv;
    __syncthreads();
    if (threadIdx.x == 0)
        atomicAdd(ws + WS_DIAG, red[0] + red[1] + red[2] + red[3]);
}

// Psplit [1024][1024]: row k = [hi(phat[k][0..512)) | lo(...)]
__global__ __launch_bounds__(256) void psplit_kernel(const float* __restrict__ out,
                                                     ushort_t* __restrict__ Ps) {
    int k = blockIdx.x, tid = threadIdx.x;
    const float2* pr = (const float2*)(out + OUT_P + (size_t)k * D);
    float2 v = pr[tid];
    ushort_t h0 = f2bf(v.x), h1 = f2bf(v.y);
    ushort_t l0 = f2bf(v.x - bf2f(h0)), l1 = f2bf(v.y - bf2f(h1));
    *(ushort2*)(Ps + (size_t)k * 1024 + 2 * tid)       = make_ushort2(h0, h1);
    *(ushort2*)(Ps + (size_t)k * 1024 + 512 + 2 * tid) = make_ushort2(l0, l1);
}

// PTsplit [512][2048]: row d = [hi(phat[0..1024)[d]) | lo(...)] (transpose of phat)
__global__ __launch_bounds__(256) void ptsplit_kernel(const float* __restrict__ out,
                                                      ushort_t* __restrict__ PT) {
    __shared__ float tile[64][65];
    int k0 = blockIdx.x * 64, d0 = blockIdx.y * 64;
    int tid = threadIdx.x;
    const float* phat = out + OUT_P;
    #pragma unroll
    for (int i = tid; i < 64 * 64; i += 256) {
        int kk = i >> 6, dd = i & 63;
        tile[dd][kk] = phat[(size_t)(k0 + kk) * D + d0 + dd];
    }
    __syncthreads();
    #pragma unroll
    for (int i = tid; i < 64 * 64; i += 256) {
        int dd = i >> 6, kk = i & 63;
        float f = tile[dd][kk];
        ushort_t hi = f2bf(f);
        ushort_t lo = f2bf(f - bf2f(hi));
        PT[(size_t)(d0 + dd) * 2048 + k0 + kk]        = hi;
        PT[(size_t)(d0 + dd) * 2048 + 1024 + k0 + kk] = lo;
    }
}

// Column sums of phat -> ||s||^2 accumulated into ws[WS_SSQ]
__global__ __launch_bounds__(256) void col_reduce_kernel(const float* __restrict__ out,
                                                         float* __restrict__ ws) {
    int d = blockIdx.x * 256 + threadIdx.x;
    const float* p = out + OUT_P;
    float s = 0.0f;
    #pragma unroll 8
    for (int k = 0; k < K; ++k) s += p[(size_t)k * D + d];
    float v = s * s;
    __shared__ float red[4];
    float w = wave_reduce_sum(v);
    int wid = threadIdx.x >> 6, lane = threadIdx.x & 63;
    if (lane == 0) red[wid] = w;
    __syncthreads();
    if (threadIdx.x == 0) atomicAdd(ws + WS_SSQ, red[0] + red[1] + red[2] + red[3]);
}

// Fused x row-norm + split: Xsplit [16384][1024] ushort (hi(512)|lo(512)) in out's pt region
__global__ __launch_bounds__(256) void xsplit_kernel(const float* __restrict__ x,
                                                     ushort_t* __restrict__ Xs) {
    int row = blockIdx.x, tid = threadIdx.x;
    const float2* xr = (const float2*)(x + (size_t)row * D);
    float2 v = xr[tid];
    float ss = v.x * v.x + v.y * v.y;
    __shared__ float red[4];
    float w = wave_reduce_sum(ss);
    int wid = tid >> 6, lane = tid & 63;
    if (lane == 0) red[wid] = w;
    __syncthreads();
    float tot = red[0] + red[1] + red[2] + red[3];
    float inv = 1.0f / fmaxf(sqrtf(tot), EPS);
    float a = v.x * inv, b = v.y * inv;
    ushort_t h0 = f2bf(a), h1 = f2bf(b);
    ushort_t l0 = f2bf(a - bf2f(h0)), l1 = f2bf(b - bf2f(h1));
    *(ushort2*)(Xs + (size_t)row * 1024 + 2 * tid)       = make_ushort2(h0, h1);
    *(ushort2*)(Xs + (size_t)row * 1024 + 512 + 2 * tid) = make_ushort2(l0, l1);
}

// Split-bf16 bt-GEMM (m97 recipe): C = sum over 3 segments of A(seg)·B(seg)^T.
template<int LDA, int LDB, int LDC, int SEGK>
__global__ __launch_bounds__(256) void gemm_bt(const ushort_t* __restrict__ A,
                                               const ushort_t* __restrict__ Bm,
                                               float* __restrict__ C,
                                               int a0, int a1, int a2,
                                               int b0, int b1, int b2) {
    __shared__ __align__(16) ushort_t As[128 * 32];
    __shared__ __align__(16) ushort_t Bs[128 * 32];
    int tid = threadIdx.x;
    int wid = tid >> 6, lane = tid & 63;
    int quad = lane >> 4, l16 = lane & 15;
    int wm = (wid & 1) * 64, wn = (wid >> 1) * 64;
    int bn0 = blockIdx.x * 128, bm0 = blockIdx.y * 128;
    int ldrow = lane >> 2;
    int lcol  = (lane & 3) * 8;

    f32x4 acc[4][4] = {};

    ushort_t* AsW0 = As + (wid * 16) * 32;
    ushort_t* AsW1 = As + (64 + wid * 16) * 32;
    ushort_t* BsW0 = Bs + (wid * 16) * 32;
    ushort_t* BsW1 = Bs + (64 + wid * 16) * 32;

    int aoff[3] = {a0, a1, a2};
    int boff[3] = {b0, b1, b2};

    for (int s = 0; s < 3; ++s) {
        const ushort_t* Ab = A + aoff[s] + (size_t)(bm0 + wid * 16 + ldrow) * LDA + lcol;
        const ushort_t* Bb = Bm + boff[s] + (size_t)(bn0 + wid * 16 + ldrow) * LDB + lcol;
        for (int kc = 0; kc < SEGK; kc += 32) {
            async16(Ab + kc, AsW0);
            async16(Ab + kc + (size_t)64 * LDA, AsW1);
            async16(Bb + kc, BsW0);
            async16(Bb + kc + (size_t)64 * LDB, BsW1);
            __syncthreads();
            bf16x8 af[4], bg[4];
            #pragma unroll
            for (int i = 0; i < 4; ++i)
                af[i] = *(const bf16x8*)(As + (wm + 16 * i + l16) * 32 + quad * 8);
            #pragma unroll
            for (int j = 0; j < 4; ++j)
                bg[j] = *(const bf16x8*)(Bs + (wn + 16 * j + l16) * 32 + quad * 8);
            #pragma unroll
            for (int i = 0; i < 4; ++i)
                #pragma unroll
                for (int j = 0; j < 4; ++j)
                    acc[i][j] = __builtin_amdgcn_mfma_f32_16x16x32_bf16(af[i], bg[j], acc[i][j], 0, 0, 0);
            __syncthreads();
        }
    }
    #pragma unroll
    for (int i = 0; i < 4; ++i) {
        #pragma unroll
        for (int j = 0; j < 4; ++j) {
            #pragma unroll
            for (int r = 0; r < 4; ++r) {
                int row = bm0 + wm + 16 * i + quad * 4 + r;
                int col = bn0 + wn + 16 * j + l16;
                C[(size_t)row * LDC + col] = acc[i][j][r];
            }
        }
    }
}

// Row softmax with gumbel. One WAVE per row (no intra-row barriers), 4 rows/wave.
// Reads sim fp32, writes Esplit bf16 (hi|lo) in-place. Per-block partial dot
// stored to ws[WS_RED + blockIdx.x] — NO contended atomics.
__global__ __launch_bounds__(256) void softmax_rows(const float* __restrict__ u,
                                                    float* __restrict__ ws) {
    float* simbuf = ws + WS_SIM;
    int tid = threadIdx.x;
    int wid = tid >> 6, lane = tid & 63;
    int gw = blockIdx.x * 4 + wid;        // 0..4095
    float dotacc = 0.0f;

    for (int r = 0; r < 4; ++r) {
        int row = gw + 4096 * r;
        const float4* srow = (const float4*)(simbuf + (size_t)row * K);
        const float4* urow = (const float4*)(u + (size_t)row * K);
        float4 s[4], z[4];
        #pragma unroll
        for (int j = 0; j < 4; ++j) {
            float4 sv = srow[lane + 64 * j];
            float4 uu = urow[lane + 64 * j];
            s[j] = sv;
            z[j].x = (sv.x - logf(-logf(uu.x))) * TAU_INV;
            z[j].y = (sv.y - logf(-logf(uu.y))) * TAU_INV;
            z[j].z = (sv.z - logf(-logf(uu.z))) * TAU_INV;
            z[j].w = (sv.w - logf(-logf(uu.w))) * TAU_INV;
        }
        float m = z[0].x;
        #pragma unroll
        for (int j = 0; j < 4; ++j) {
            m = fmaxf(m, fmaxf(fmaxf(z[j].x, z[j].y), fmaxf(z[j].z, z[j].w)));
        }
        m = wave_reduce_max(m);
        m = __shfl(m, 0);

        float4 e[4];
        float l = 0.0f;
        #pragma unroll
        for (int j = 0; j < 4; ++j) {
            e[j].x = expf(z[j].x - m);
            e[j].y = expf(z[j].y - m);
            e[j].z = expf(z[j].z - m);
            e[j].w = expf(z[j].w - m);
            l += e[j].x + e[j].y + e[j].z + e[j].w;
        }
        l = wave_reduce_sum(l);
        l = __shfl(l, 0);
        float inv = 1.0f / l;

        ushort_t* erow = (ushort_t*)(simbuf + (size_t)row * K);
        #pragma unroll
        for (int j = 0; j < 4; ++j) {
            float ex = e[j].x * inv, ey = e[j].y * inv,
                  ez = e[j].z * inv, ew = e[j].w * inv;
            ushort_t h0 = f2bf(ex), h1 = f2bf(ey), h2 = f2bf(ez), h3 = f2bf(ew);
            ushort4 hi4 = make_ushort4(h0, h1, h2, h3);
            ushort4 lo4 = make_ushort4(f2bf(ex - bf2f(h0)), f2bf(ey - bf2f(h1)),
                                       f2bf(ez - bf2f(h2)), f2bf(ew - bf2f(h3)));
            *(ushort4*)(erow + 4 * (lane + 64 * j))        = hi4;
            *(ushort4*)(erow + 1024 + 4 * (lane + 64 * j)) = lo4;
            dotacc += ex * s[j].x + ey * s[j].y + ez * s[j].z + ew * s[j].w;
        }
    }

    dotacc = wave_reduce_sum(dotacc);
    __shared__ float red[4];
    if (lane == 0) red[wid] = dotacc;
    __syncthreads();
    if (tid == 0) ws[WS_RED + blockIdx.x] = red[0] + red[1] + red[2] + red[3];
}

__global__ __launch_bounds__(256) void finalize_kernel(float* __restrict__ out,
                                                       const float* __restrict__ ws) {
    int tid = threadIdx.x, wid = tid >> 6, lane = tid & 63;
    float v = 0.0f;
    #pragma unroll
    for (int i = 0; i < 4; ++i) v += ws[WS_RED + tid + 256 * i];
    v = wave_reduce_sum(v);
    __shared__ float red[4];
    if (lane == 0) red[wid] = v;
    __syncthreads();
    if (tid == 0) {
        float dot = red[0] + red[1] + red[2] + red[3];
        out[OUT_SIM] = 1.0f - dot * (1.0f / (float)B);
        out[OUT_DIV] = ws[WS_SSQ] - ws[WS_DIAG];
    }
}

extern "C" void kernel_launch(void* const* d_in, const int* in_sizes, int n_in,
                              void* d_out, int out_size, void* d_ws, size_t ws_size,
                              hipStream_t stream) {
    const float* input  = (const float*)d_in[0];
    const float* proto  = (const float*)d_in[1];
    const float* gumbel = (const float*)d_in[2];
    float* out = (float*)d_out;
    float* ws  = (float*)d_ws;

    ushort_t* Xs  = (ushort_t*)(out + OUT_PT);     // Xsplit scratch in pt region
    ushort_t* Ps  = (ushort_t*)(ws + WS_PS);
    ushort_t* PTs = (ushort_t*)(ws + WS_PTS);
    ushort_t* Es  = (ushort_t*)(ws + WS_SIM);      // Esplit aliases sim rows
    float* sim = ws + WS_SIM;

    zero_scalars<<<1, 64, 0, stream>>>(ws);
    norm_p_kernel<<<K / 4, 256, 0, stream>>>(proto, out, ws);
    psplit_kernel<<<K, 256, 0, stream>>>(out, Ps);
    {
        dim3 grid(K / 64, D / 64);
        ptsplit_kernel<<<grid, 256, 0, stream>>>(out, PTs);
    }
    col_reduce_kernel<<<D / 256, 256, 0, stream>>>(out, ws);
    xsplit_kernel<<<B, 256, 0, stream>>>(input, Xs);
    {
        // sim = Xhi·Phi^T + Xhi·Plo^T + Xlo·Phi^T
        dim3 grid(K / 128, B / 128);
        gemm_bt<1024, 1024, K, 512><<<grid, 256, 0, stream>>>(
            Xs, Ps, sim, 0, 0, 512, 0, 512, 0);
    }
    softmax_rows<<<1024, 256, 0, stream>>>(gumbel, ws);
    {
        // pt = Ehi·PThi^T + Elo·PThi^T + Ehi·PTlo^T
        dim3 grid(D / 128, B / 128);
        gemm_bt<2048, 2048, D, 1024><<<grid, 256, 0, stream>>>(
            Es, PTs, out + OUT_PT, 0, 1024, 0, 0, 0, 1024);
    }
    finalize_kernel<<<1, 256, 0, stream>>>(out, ws);
}

// Round 4
// 234.105 us; speedup vs baseline: 3.9359x; 1.6910x over previous
//
#include <hip/hip_runtime.h>
#include <hip/hip_bf16.h>
#include <math.h>

// Problem constants
#define B  16384
#define K  1024
#define D  512
#define TAU_INV 10.0f
#define EPS 1e-12f

typedef unsigned short ushort_t;

// d_out layout (floats): [0, B*D) pt ; [B*D, B*D+K*D) p ; then sim_loss, div_loss
#define OUT_PT   0
#define OUT_P    (B*D)
#define OUT_SIM  (B*D + K*D)
#define OUT_DIV  (B*D + K*D + 1)

// ws layout (floats):
//  [0..16)        scalars: 2=diag sum
//  [1024,2048)    softmax per-block dot partials (1024)
//  [2048,2560)    colsum[512] (atomic-accumulated)
//  [32768, +B*K)  sim fp32; after softmax row's first 2KB hold Eh f16 in-place
//  then Ph  [1024][512] f16  (1 MB)  — gemm1 B operand
//  then PTh [512][1024] f16  (1 MB)  — gemm2 B operand (p transposed)
#define WS_DIAG  2
#define WS_RED   1024
#define WS_COL   2048
#define WS_SIM   32768
#define WS_PH    (WS_SIM + B*K)
#define WS_PTH   (WS_PH + (K*D)/2)

// Xh f16 [16384][512] (16 MB) lives in d_out's pt region, consumed by gemm1
// before gemm2 overwrites pt.

typedef _Float16 half8 __attribute__((ext_vector_type(8)));
typedef float f32x4 __attribute__((ext_vector_type(4)));

__device__ __forceinline__ float wave_reduce_sum(float v) {
    #pragma unroll
    for (int off = 32; off >= 1; off >>= 1) v += __shfl_down(v, off);
    return v;
}
__device__ __forceinline__ float wave_reduce_max(float v) {
    #pragma unroll
    for (int off = 32; off >= 1; off >>= 1) v = fmaxf(v, __shfl_down(v, off));
    return v;
}

__device__ __forceinline__ ushort_t f2h(float f) {
    _Float16 h = (_Float16)f;
    return __builtin_bit_cast(ushort_t, h);
}

__device__ __forceinline__ void async16(const void* g, void* l) {
    __builtin_amdgcn_global_load_lds(
        (const __attribute__((address_space(1))) unsigned int*)g,
        (__attribute__((address_space(3))) unsigned int*)l, 16, 0, 0);
}

// Zero scalars + colsum
__global__ __launch_bounds__(256) void zero_ws(float* ws) {
    int t = threadIdx.x;
    if (t < 16) ws[t] = 0.0f;
    ws[WS_COL + t] = 0.0f;
    ws[WS_COL + 256 + t] = 0.0f;
}

// Normalize prototypes: one wave per row. Writes phat (fp32) to d_out.
// One atomic per block for the diag sum.
__global__ __launch_bounds__(256) void norm_p_kernel(const float* __restrict__ proto,
                                                     float* __restrict__ out,
                                                     float* __restrict__ ws) {
    int wid = threadIdx.x >> 6, lane = threadIdx.x & 63;
    int row = blockIdx.x * 4 + wid;
    const float4* pr = (const float4*)(proto + (size_t)row * D);
    float4 a = pr[lane * 2], b = pr[lane * 2 + 1];
    float ss = a.x*a.x + a.y*a.y + a.z*a.z + a.w*a.w
             + b.x*b.x + b.y*b.y + b.z*b.z + b.w*b.w;
    ss = wave_reduce_sum(ss);
    ss = __shfl(ss, 0);
    float inv = 1.0f / fmaxf(sqrtf(ss), EPS);
    float4* po = (float4*)(out + OUT_P + (size_t)row * D);
    po[lane * 2]     = make_float4(a.x*inv, a.y*inv, a.z*inv, a.w*inv);
    po[lane * 2 + 1] = make_float4(b.x*inv, b.y*inv, b.z*inv, b.w*inv);
    __shared__ float red[4];
    if (lane == 0) red[wid] = ss * inv * inv;
    __syncthreads();
    if (threadIdx.x == 0)
        atomicAdd(ws + WS_DIAG, red[0] + red[1] + red[2] + red[3]);
}

// Ph [1024][512] f16: phat rows converted
__global__ __launch_bounds__(256) void pcvt_kernel(const float* __restrict__ out,
                                                   ushort_t* __restrict__ Ph) {
    int k = blockIdx.x, tid = threadIdx.x;
    const float2* pr = (const float2*)(out + OUT_P + (size_t)k * D);
    float2 v = pr[tid];
    *(ushort2*)(Ph + (size_t)k * D + 2 * tid) = make_ushort2(f2h(v.x), f2h(v.y));
}

// PTh [512][1024] f16: transpose of phat
__global__ __launch_bounds__(256) void ptcvt_kernel(const float* __restrict__ out,
                                                    ushort_t* __restrict__ PT) {
    __shared__ float tile[64][65];
    int k0 = blockIdx.x * 64, d0 = blockIdx.y * 64;
    int tid = threadIdx.x;
    const float* phat = out + OUT_P;
    #pragma unroll
    for (int i = tid; i < 64 * 64; i += 256) {
        int kk = i >> 6, dd = i & 63;
        tile[dd][kk] = phat[(size_t)(k0 + kk) * D + d0 + dd];
    }
    __syncthreads();
    #pragma unroll
    for (int i = tid; i < 64 * 64; i += 256) {
        int dd = i >> 6, kk = i & 63;
        PT[(size_t)(d0 + dd) * K + k0 + kk] = f2h(tile[dd][kk]);
    }
}

// Column-sum partials: 32 blocks, block b sums k in [32b,32b+32), coalesced.
__global__ __launch_bounds__(256) void col_partial(const float* __restrict__ out,
                                                   float* __restrict__ ws) {
    int d = threadIdx.x * 2;
    const float* p = out + OUT_P + (size_t)blockIdx.x * 32 * D;
    float sx = 0.0f, sy = 0.0f;
    #pragma unroll
    for (int kk = 0; kk < 32; ++kk) {
        float2 v = *(const float2*)(p + (size_t)kk * D + d);
        sx += v.x; sy += v.y;
    }
    atomicAdd(ws + WS_COL + d, sx);
    atomicAdd(ws + WS_COL + d + 1, sy);
}

// Fused x row-norm + f16 convert: Xh [16384][512] in out's pt region.
// One wave per row, 4 rows per block.
__global__ __launch_bounds__(256) void xcvt_kernel(const float* __restrict__ x,
                                                   ushort_t* __restrict__ Xh) {
    int wid = threadIdx.x >> 6, lane = threadIdx.x & 63;
    int row = blockIdx.x * 4 + wid;
    const float4* xr = (const float4*)(x + (size_t)row * D);
    float4 a = xr[lane * 2], b = xr[lane * 2 + 1];
    float ss = a.x*a.x + a.y*a.y + a.z*a.z + a.w*a.w
             + b.x*b.x + b.y*b.y + b.z*b.z + b.w*b.w;
    ss = wave_reduce_sum(ss);
    ss = __shfl(ss, 0);
    float inv = 1.0f / fmaxf(sqrtf(ss), EPS);
    ushort4 h0 = make_ushort4(f2h(a.x*inv), f2h(a.y*inv), f2h(a.z*inv), f2h(a.w*inv));
    ushort4 h1 = make_ushort4(f2h(b.x*inv), f2h(b.y*inv), f2h(b.z*inv), f2h(b.w*inv));
    ushort4* xo = (ushort4*)(Xh + (size_t)row * D);
    xo[lane * 2]     = h0;
    xo[lane * 2 + 1] = h1;
}

// f16 bt-GEMM (m97 recipe): C[m][n] = A·B^T. 128x128 block tile, 4 waves,
// 4x4 16x16x32-f16 MFMA tiles per wave, BK=32, global_load_lds width-16.
template<int LDA, int LDB, int LDC, int SEGK>
__global__ __launch_bounds__(256) void gemm_bt(const ushort_t* __restrict__ A,
                                               const ushort_t* __restrict__ Bm,
                                               float* __restrict__ C) {
    __shared__ __align__(16) ushort_t As[128 * 32];
    __shared__ __align__(16) ushort_t Bs[128 * 32];
    int tid = threadIdx.x;
    int wid = tid >> 6, lane = tid & 63;
    int quad = lane >> 4, l16 = lane & 15;
    int wm = (wid & 1) * 64, wn = (wid >> 1) * 64;
    int bn0 = blockIdx.x * 128, bm0 = blockIdx.y * 128;
    int ldrow = lane >> 2;
    int lcol  = (lane & 3) * 8;

    f32x4 acc[4][4] = {};

    ushort_t* AsW0 = As + (wid * 16) * 32;
    ushort_t* AsW1 = As + (64 + wid * 16) * 32;
    ushort_t* BsW0 = Bs + (wid * 16) * 32;
    ushort_t* BsW1 = Bs + (64 + wid * 16) * 32;

    const ushort_t* Ab = A + (size_t)(bm0 + wid * 16 + ldrow) * LDA + lcol;
    const ushort_t* Bb = Bm + (size_t)(bn0 + wid * 16 + ldrow) * LDB + lcol;

    for (int kc = 0; kc < SEGK; kc += 32) {
        async16(Ab + kc, AsW0);
        async16(Ab + kc + (size_t)64 * LDA, AsW1);
        async16(Bb + kc, BsW0);
        async16(Bb + kc + (size_t)64 * LDB, BsW1);
        __syncthreads();
        half8 af[4], bg[4];
        #pragma unroll
        for (int i = 0; i < 4; ++i)
            af[i] = *(const half8*)(As + (wm + 16 * i + l16) * 32 + quad * 8);
        #pragma unroll
        for (int j = 0; j < 4; ++j)
            bg[j] = *(const half8*)(Bs + (wn + 16 * j + l16) * 32 + quad * 8);
        #pragma unroll
        for (int i = 0; i < 4; ++i)
            #pragma unroll
            for (int j = 0; j < 4; ++j)
                acc[i][j] = __builtin_amdgcn_mfma_f32_16x16x32_f16(af[i], bg[j], acc[i][j], 0, 0, 0);
        __syncthreads();
    }
    #pragma unroll
    for (int i = 0; i < 4; ++i) {
        #pragma unroll
        for (int j = 0; j < 4; ++j) {
            #pragma unroll
            for (int r = 0; r < 4; ++r) {
                int row = bm0 + wm + 16 * i + quad * 4 + r;
                int col = bn0 + wn + 16 * j + l16;
                C[(size_t)row * LDC + col] = acc[i][j][r];
            }
        }
    }
}

// Row softmax with gumbel. One WAVE per row, 4 rows/wave. Reads sim fp32,
// writes Eh f16 in-place over the row's first 2KB. Per-block dot partial.
__global__ __launch_bounds__(256) void softmax_rows(const float* __restrict__ u,
                                                    float* __restrict__ ws) {
    float* simbuf = ws + WS_SIM;
    int tid = threadIdx.x;
    int wid = tid >> 6, lane = tid & 63;
    int gw = blockIdx.x * 4 + wid;        // 0..4095
    float dotacc = 0.0f;

    for (int r = 0; r < 4; ++r) {
        int row = gw + 4096 * r;
        const float4* srow = (const float4*)(simbuf + (size_t)row * K);
        const float4* urow = (const float4*)(u + (size_t)row * K);
        float4 s[4], z[4];
        #pragma unroll
        for (int j = 0; j < 4; ++j) {
            float4 sv = srow[lane + 64 * j];
            float4 uu = urow[lane + 64 * j];
            s[j] = sv;
            z[j].x = (sv.x - logf(-logf(uu.x))) * TAU_INV;
            z[j].y = (sv.y - logf(-logf(uu.y))) * TAU_INV;
            z[j].z = (sv.z - logf(-logf(uu.z))) * TAU_INV;
            z[j].w = (sv.w - logf(-logf(uu.w))) * TAU_INV;
        }
        float m = z[0].x;
        #pragma unroll
        for (int j = 0; j < 4; ++j)
            m = fmaxf(m, fmaxf(fmaxf(z[j].x, z[j].y), fmaxf(z[j].z, z[j].w)));
        m = wave_reduce_max(m);
        m = __shfl(m, 0);

        float4 e[4];
        float l = 0.0f;
        #pragma unroll
        for (int j = 0; j < 4; ++j) {
            e[j].x = expf(z[j].x - m);
            e[j].y = expf(z[j].y - m);
            e[j].z = expf(z[j].z - m);
            e[j].w = expf(z[j].w - m);
            l += e[j].x + e[j].y + e[j].z + e[j].w;
        }
        l = wave_reduce_sum(l);
        l = __shfl(l, 0);
        float inv = 1.0f / l;

        ushort_t* erow = (ushort_t*)(simbuf + (size_t)row * K);
        #pragma unroll
        for (int j = 0; j < 4; ++j) {
            float ex = e[j].x * inv, ey = e[j].y * inv,
                  ez = e[j].z * inv, ew = e[j].w * inv;
            *(ushort4*)(erow + 4 * (lane + 64 * j)) =
                make_ushort4(f2h(ex), f2h(ey), f2h(ez), f2h(ew));
            dotacc += ex * s[j].x + ey * s[j].y + ez * s[j].z + ew * s[j].w;
        }
    }

    dotacc = wave_reduce_sum(dotacc);
    __shared__ float red[4];
    if (lane == 0) red[wid] = dotacc;
    __syncthreads();
    if (tid == 0) ws[WS_RED + blockIdx.x] = red[0] + red[1] + red[2] + red[3];
}

__global__ __launch_bounds__(256) void finalize_kernel(float* __restrict__ out,
                                                       const float* __restrict__ ws) {
    int tid = threadIdx.x, wid = tid >> 6, lane = tid & 63;
    float vdot = 0.0f;
    #pragma unroll
    for (int i = 0; i < 4; ++i) vdot += ws[WS_RED + tid + 256 * i];
    float c0 = ws[WS_COL + tid], c1 = ws[WS_COL + 256 + tid];
    float vssq = c0 * c0 + c1 * c1;
    vdot = wave_reduce_sum(vdot);
    vssq = wave_reduce_sum(vssq);
    __shared__ float rd[4], rs[4];
    if (lane == 0) { rd[wid] = vdot; rs[wid] = vssq; }
    __syncthreads();
    if (tid == 0) {
        float dot = rd[0] + rd[1] + rd[2] + rd[3];
        float ssq = rs[0] + rs[1] + rs[2] + rs[3];
        out[OUT_SIM] = 1.0f - dot * (1.0f / (float)B);
        out[OUT_DIV] = ssq - ws[WS_DIAG];
    }
}

extern "C" void kernel_launch(void* const* d_in, const int* in_sizes, int n_in,
                              void* d_out, int out_size, void* d_ws, size_t ws_size,
                              hipStream_t stream) {
    const float* input  = (const float*)d_in[0];
    const float* proto  = (const float*)d_in[1];
    const float* gumbel = (const float*)d_in[2];
    float* out = (float*)d_out;
    float* ws  = (float*)d_ws;

    ushort_t* Xh  = (ushort_t*)(out + OUT_PT);     // f16 x-hat in pt region
    ushort_t* Ph  = (ushort_t*)(ws + WS_PH);
    ushort_t* PTh = (ushort_t*)(ws + WS_PTH);
    ushort_t* Eh  = (ushort_t*)(ws + WS_SIM);      // f16 e aliases sim rows
    float* sim = ws + WS_SIM;

    zero_ws<<<1, 256, 0, stream>>>(ws);
    norm_p_kernel<<<K / 4, 256, 0, stream>>>(proto, out, ws);
    pcvt_kernel<<<K, 256, 0, stream>>>(out, Ph);
    {
        dim3 grid(K / 64, D / 64);
        ptcvt_kernel<<<grid, 256, 0, stream>>>(out, PTh);
    }
    col_partial<<<K / 32, 256, 0, stream>>>(out, ws);
    xcvt_kernel<<<B / 4, 256, 0, stream>>>(input, Xh);
    {
        // sim = Xh · Ph^T   (A: [B][512], B: [K][512], C: [B][K] fp32)
        dim3 grid(K / 128, B / 128);
        gemm_bt<512, 512, K, 512><<<grid, 256, 0, stream>>>(Xh, Ph, sim);
    }
    softmax_rows<<<1024, 256, 0, stream>>>(gumbel, ws);
    {
        // pt = Eh · PTh^T   (A: [B][1024] with row stride 2048 halves,
        //                    B: [512][1024], C: [B][512] fp32)
        dim3 grid(D / 128, B / 128);
        gemm_bt<2048, 1024, D, 1024><<<grid, 256, 0, stream>>>(Eh, PTh, out + OUT_PT);
    }
    finalize_kernel<<<1, 256, 0, stream>>>(out, ws);
}